// Round 2
// baseline (235.937 us; speedup 1.0000x reference)
//
#include <hip/hip_runtime.h>

// Walsh-Hadamard transform, N=4096 per row, fp32, scale 1/sqrt(4096)=1/64.
// H_4096 = H_16 (x) H_16 (x) H_16  -> three WHT16 passes over hex digits
// a=bits0-3, b=bits4-7, c=bits8-11, with two padded-LDS transposes between.
//
// R2 change: persistent blocks. grid = 2048 (8 blocks/CU x 256 CUs), each
// block processes 4 consecutive rows, prefetching row i+1's 4 float4s into
// registers BEFORE row i's compute/LDS phases. Rationale: R1 showed the
// kernel is not occupancy-bound; theory is bursty VMEM demand (load burst ->
// barrier-locked LDS phases with VMEM idle -> store burst) caps us at
// ~4 TB/s vs 6.3 achievable. Prefetch keeps HBM reads in flight through the
// barrier phases and removes 3/4 of block launch/drain boundaries.
// VGPR budget: 16 data + 16 prefetch + addressing ~= 50 < 64, keeps 8 waves/SIMD.

constexpr int N = 4096;
constexpr int LDS_STRIDE = 17;          // 16 + 1 pad: odd stride -> only free 2-way conflicts
constexpr int ROWS_PER_BLOCK = 4;

__device__ __forceinline__ void wht16(float v[16]) {
#pragma unroll
    for (int m = 1; m < 16; m <<= 1) {
#pragma unroll
        for (int g = 0; g < 16; g += 2 * m) {
#pragma unroll
            for (int k = 0; k < m; ++k) {
                float a = v[g + k];
                float b = v[g + k + m];
                v[g + k]     = a + b;
                v[g + k + m] = a - b;
            }
        }
    }
}

__global__ __launch_bounds__(256, 8) void fwht4096_kernel(const float* __restrict__ in,
                                                          float* __restrict__ out,
                                                          int rows) {
    // logical index within a row: e = c*256 + b*16 + a   (a,b,c in [0,16))
    // LDS physical map for a logical 256x16 tile: phys(i) = (i>>4)*17 + (i&15)
    __shared__ float lds[256 * LDS_STRIDE];

    const int t = threadIdx.x;
    const size_t row0 = (size_t)blockIdx.x * ROWS_PER_BLOCK;

    float v[16];
    float4 f0, f1, f2, f3;

    // ---- prime the pipeline: load row0 (thread t holds e = t*16 + j) ----
    {
        const float4* s4 = (const float4*)(in + row0 * (size_t)N + t * 16);
        f0 = s4[0]; f1 = s4[1]; f2 = s4[2]; f3 = s4[3];
    }

#pragma unroll
    for (int i = 0; i < ROWS_PER_BLOCK; ++i) {
        const size_t row = row0 + i;
        if (row >= (size_t)rows) break;
        float* __restrict__ dst = out + row * (size_t)N;

        // unpack the (pre)fetched registers into v
        v[0]=f0.x;  v[1]=f0.y;  v[2]=f0.z;  v[3]=f0.w;
        v[4]=f1.x;  v[5]=f1.y;  v[6]=f1.z;  v[7]=f1.w;
        v[8]=f2.x;  v[9]=f2.y;  v[10]=f2.z; v[11]=f2.w;
        v[12]=f3.x; v[13]=f3.y; v[14]=f3.z; v[15]=f3.w;

        // issue next row's loads NOW — they complete during the 3 WHT passes,
        // 4 barriers and 2 LDS transposes below.
        if (i + 1 < ROWS_PER_BLOCK && row + 1 < (size_t)rows) {
            const float4* p4 = (const float4*)(in + (row + 1) * (size_t)N + t * 16);
            f0 = p4[0]; f1 = p4[1]; f2 = p4[2]; f3 = p4[3];
        }

        wht16(v);   // digit a done

        // protect LDS from the previous iteration's reads before overwriting
        if (i > 0) __syncthreads();

        // ---- transpose 1: logical layout i = c*256 + a*16 + b ----
        // writer: idx = (t>>4)*256 + j*16 + (t&15) -> phys = ((t>>4)*16 + j)*17 + (t&15)
        {
            const int base = (t >> 4) * (16 * LDS_STRIDE) + (t & 15);
#pragma unroll
            for (int j = 0; j < 16; ++j) lds[base + j * LDS_STRIDE] = v[j];
        }
        __syncthreads();
        // reader: idx = t*16 + p  (c=t>>4, a=t&15, b=p) -> phys = t*17 + p (contiguous)
        {
            const int base = t * LDS_STRIDE;
#pragma unroll
            for (int p = 0; p < 16; ++p) v[p] = lds[base + p];
        }
        wht16(v);   // digit b done
        __syncthreads();   // protect LDS before overwrite

        // ---- transpose 2: logical layout i = b*256 + a*16 + c ----
        // writer: idx = j*256 + (t&15)*16 + (t>>4) -> phys = (j*16 + (t&15))*17 + (t>>4)
        {
            const int base = (t & 15) * LDS_STRIDE + (t >> 4);
#pragma unroll
            for (int j = 0; j < 16; ++j) lds[base + j * (16 * LDS_STRIDE)] = v[j];
        }
        __syncthreads();
        // reader: idx = t*16 + p  (b=t>>4, a=t&15, c=p) -> phys = t*17 + p
        {
            const int base = t * LDS_STRIDE;
#pragma unroll
            for (int p = 0; p < 16; ++p) v[p] = lds[base + p];
        }
        wht16(v);   // digit c done

        // ---- store: element e = p*256 + (t>>4)*16 + (t&15) = p*256 + t ----
        const float scale = 0.015625f;  // 1/64 = 1/sqrt(4096)
#pragma unroll
        for (int p = 0; p < 16; ++p) dst[p * 256 + t] = v[p] * scale;
    }
}

extern "C" void kernel_launch(void* const* d_in, const int* in_sizes, int n_in,
                              void* d_out, int out_size, void* d_ws, size_t ws_size,
                              hipStream_t stream) {
    const float* x = (const float*)d_in[0];
    float* y = (float*)d_out;
    const int rows = in_sizes[0] / N;   // 4*2048 = 8192
    const int blocks = (rows + ROWS_PER_BLOCK - 1) / ROWS_PER_BLOCK;  // 2048
    fwht4096_kernel<<<blocks, 256, 0, stream>>>(x, y, rows);
}